// Round 10
// baseline (278.068 us; speedup 1.0000x reference)
//
#include <hip/hip_runtime.h>
#include <hip/hip_bf16.h>
#include <stdint.h>

// Problem constants (B=8, S=8192, K=1024, N=1024, G=128)
#define M_DIM 65536
#define K_DIM 1024
#define N_DIM 1024
#define NGRP  8

// 128x128 i8 GEMM, BK=64, 3-deep ring + counted vmcnt (r9 + latency distance)
#define T_BM 128
#define T_BN 128
#define T_BK 64
#define T_NKT (K_DIM / T_BK)    // 16

// fallback geometry (round-1 fused kernel)
#define FB_BM 128
#define FB_BN 128
#define FB_BK 32
#define FB_NKT (K_DIM / FB_BK)

typedef float f32x4 __attribute__((ext_vector_type(4)));
typedef int   ix4   __attribute__((ext_vector_type(4)));
typedef __bf16 bf16x8 __attribute__((ext_vector_type(8)));

// ---------------- prep: wd = w_q - w_zp (int8) [N][K], bias -> f32 ----------------
__global__ void prep_wd_kernel(const int* __restrict__ w_q,
                               const int* __restrict__ w_zp,
                               const int* __restrict__ bias_q,
                               const float* __restrict__ bias_scale,
                               int8_t* __restrict__ Wd,
                               float* __restrict__ bias_f) {
    const int n = blockIdx.x;       // 0..1023
    const int t = threadIdx.x;      // 0..255
    const int k0 = t * 4;
    const int g = k0 >> 7;
    const int zp = w_zp[n * NGRP + g];
    const int4 wq = *reinterpret_cast<const int4*>(w_q + (size_t)n * K_DIM + k0);
    union { int u; int8_t b[4]; } pk;
    pk.b[0] = (int8_t)(wq.x - zp);
    pk.b[1] = (int8_t)(wq.y - zp);
    pk.b[2] = (int8_t)(wq.z - zp);
    pk.b[3] = (int8_t)(wq.w - zp);
    *reinterpret_cast<int*>(Wd + (size_t)n * K_DIM + k0) = pk.u;
    if (t == 0) bias_f[n] = ((float)bias_q[n] - 128.0f) * bias_scale[n];
}

// ---------------- prep: fake-quant x -> int8 codes [M][K] ----------------
__global__ __launch_bounds__(256) void prep_x8_kernel(
    const float* __restrict__ x,
    const float* __restrict__ in_scale_p, const int* __restrict__ in_zp_p,
    int8_t* __restrict__ Xq)
{
    const float s = in_scale_p[0];
    const float inv = 1.0f / s;
    const float zp = (float)in_zp_p[0];
    const size_t i = ((size_t)blockIdx.x * 256 + threadIdx.x) * 16;
    float vv[16];
#pragma unroll
    for (int c = 0; c < 4; ++c) {
        const float4 v = *reinterpret_cast<const float4*>(x + i + c * 4);
        vv[c * 4 + 0] = v.x; vv[c * 4 + 1] = v.y;
        vv[c * 4 + 2] = v.z; vv[c * 4 + 3] = v.w;
    }
    union { int4 u; int8_t b[16]; } pk;
#pragma unroll
    for (int e = 0; e < 16; ++e) {
        float q = rintf(vv[e] * inv) + zp;       // RNE matches jnp.round
        q = fminf(fmaxf(q, -128.0f), 127.0f);
        pk.b[e] = (int8_t)(q - zp);
    }
    *reinterpret_cast<int4*>(Xq + i) = pk.u;
}

// ---------------- 128x128 i8 GEMM: 3-deep ring, counted vmcnt, raw barrier ----------------
// Identical to r9 except the sync structure:
//   LDS = 3 x (A 8KB + B 8KB) ring + WS 4KB = 52 KB -> 3 blocks/CU.
//   Per tile kt: { stage kt+2 (4 loads/thread) | ds_read frags of kt |
//                  16 MFMA i8 + per-tile CVT | vmcnt(4) | sched_bar
//                  s_barrier sched_bar }.
// Ledger (4 loads/thread/tile, FIFO retirement per m135):
//   prologue: stage t0,t1 (8) -> vmcnt(4) retires t0 -> lgkm(0) (WS) -> barrier.
//   end of tile kt<=13: outstanding = {kt+1, kt+2} = 8 -> vmcnt(4) retires
//     kt+1 (staged 2 tiles = ~1000+ cyc earlier -> HBM latency covered).
//   kt=14: outstanding = {t15} -> vmcnt(0). kt=15: none.
// WAR: stage into buf (kt+2)%3 issued after the barrier closing tile kt-1;
//   that tile's ds_reads were drained by their MFMA data-deps before it.
__global__ __launch_bounds__(256) void gemm128_i8_kernel(
    const int8_t* __restrict__ Xq,
    const int8_t* __restrict__ Wd,
    const float* __restrict__ w_scale,
    const float* __restrict__ bias_f,
    const float* __restrict__ in_scale_p,
    const float* __restrict__ out_scale_p, const int* __restrict__ out_zp_p,
    float* __restrict__ out)
{
    __shared__ __align__(16) int8_t Abuf[3][T_BM * T_BK];   // 3 x 8 KB
    __shared__ __align__(16) int8_t Bbuf[3][T_BN * T_BK];   // 3 x 8 KB
    __shared__ float WS[NGRP * T_BN];                        // 4 KB [g][n_local]

    const int t = threadIdx.x;
    // bijective XCD swizzle: grid=4096, 8 XCDs, 512 blocks/XCD;
    // consecutive local bids share the A panel (mt) across nt=0..7.
    const int bid = (blockIdx.x & 7) * 512 + (blockIdx.x >> 3);
    const int nt = bid & 7;
    const int mt = bid >> 3;
    const int m0 = mt * T_BM;
    const int n0 = nt * T_BN;

    const int wid = t >> 6;
    const int lane = t & 63;
    const int wr = wid >> 1, wc = wid & 1;     // 2x2 waves, each owns 64x64
    const int lrow = lane & 15;
    const int kslot = lane >> 4;               // 16B k-chunk within 64B row
    const int koff = ((kslot ^ ((lrow >> 1) & 3)) << 4);   // 0-conflict (r2-r9)
    const int widoff = wid * 1024;

    const int8_t* Abase = Xq + (size_t)m0 * K_DIM;
    const int8_t* Bbase = Wd + (size_t)n0 * K_DIM;

    // ---- preload w_scale panel [g][n_local] (drained before first barrier) ----
    {
        const int nl = t >> 1;                 // 0..127
        const int g4 = (t & 1) * 4;
        const float4 wv = *reinterpret_cast<const float4*>(
            w_scale + (size_t)(n0 + nl) * NGRP + g4);
        WS[(g4 + 0) * T_BN + nl] = wv.x;
        WS[(g4 + 1) * T_BN + nl] = wv.y;
        WS[(g4 + 2) * T_BN + nl] = wv.z;
        WS[(g4 + 3) * T_BN + nl] = wv.w;
    }

    // stage one 128x64B tile (512 chunks, 2/thread), pre-swizzled source
    auto stage = [&](int8_t* dst, const int8_t* panel, int kt) {
        const int k0 = kt * T_BK;
#pragma unroll
        for (int j = 0; j < 2; ++j) {
            const int c = j * 256 + t;                 // 16B chunk id 0..511
            const int r = c >> 2;                      // row 0..127
            const int sl = (c & 3) ^ ((r >> 1) & 3);   // logical k-slot at phys slot
            const int8_t* src = panel + (size_t)r * K_DIM + k0 + sl * 16;
            __builtin_amdgcn_global_load_lds(
                (const __attribute__((address_space(1))) void*)src,
                (__attribute__((address_space(3))) void*)(dst + j * 4096 + widoff),
                16, 0, 0);
        }
    };

    f32x4 facc[4][4];
#pragma unroll
    for (int mi = 0; mi < 4; ++mi)
#pragma unroll
        for (int ni = 0; ni < 4; ++ni)
            facc[mi][ni] = (f32x4){0.f, 0.f, 0.f, 0.f};

    // prologue: stage tiles 0,1; retire tile 0; drain WS writes; rendezvous
    stage(&Abuf[0][0], Abase, 0);
    stage(&Bbuf[0][0], Bbase, 0);
    stage(&Abuf[1][0], Abase, 1);
    stage(&Bbuf[1][0], Bbase, 1);
    asm volatile("s_waitcnt vmcnt(4) lgkmcnt(0)" ::: "memory");
    __builtin_amdgcn_s_barrier();
    __builtin_amdgcn_sched_barrier(0);

#pragma unroll 1
    for (int kt = 0; kt < T_NKT; ++kt) {
        const int cb = kt % 3;
        const int nb = (kt + 2) % 3;
        if (kt + 2 < T_NKT) {
            stage(&Abuf[nb][0], Abase, kt + 2);
            stage(&Bbuf[nb][0], Bbase, kt + 2);
        }

        ix4 af[4], bfr[4];
#pragma unroll
        for (int i = 0; i < 4; ++i) {
            const int arow = wr * 64 + i * 16 + lrow;
            af[i] = *reinterpret_cast<const ix4*>(&Abuf[cb][arow * 64 + koff]);
        }
#pragma unroll
        for (int i = 0; i < 4; ++i) {
            const int brow = wc * 64 + i * 16 + lrow;
            bfr[i] = *reinterpret_cast<const ix4*>(&Bbuf[cb][brow * 64 + koff]);
        }

        const int g = kt >> 1;
        float wsv[4];
#pragma unroll
        for (int ni = 0; ni < 4; ++ni)
            wsv[ni] = WS[g * T_BN + wc * 64 + ni * 16 + lrow];

#pragma unroll
        for (int mi = 0; mi < 4; ++mi) {
            ix4 s0 = __builtin_amdgcn_mfma_i32_16x16x64_i8(af[mi], bfr[0], (ix4){0,0,0,0}, 0, 0, 0);
            ix4 s1 = __builtin_amdgcn_mfma_i32_16x16x64_i8(af[mi], bfr[1], (ix4){0,0,0,0}, 0, 0, 0);
            ix4 s2 = __builtin_amdgcn_mfma_i32_16x16x64_i8(af[mi], bfr[2], (ix4){0,0,0,0}, 0, 0, 0);
            ix4 s3 = __builtin_amdgcn_mfma_i32_16x16x64_i8(af[mi], bfr[3], (ix4){0,0,0,0}, 0, 0, 0);
#pragma unroll
            for (int e = 0; e < 4; ++e) {
                facc[mi][0][e] += wsv[0] * (float)s0[e];
                facc[mi][1][e] += wsv[1] * (float)s1[e];
                facc[mi][2][e] += wsv[2] * (float)s2[e];
                facc[mi][3][e] += wsv[3] * (float)s3[e];
            }
        }

        // counted retirement wait + raw barrier (no vmcnt(0) drain in steady state)
        if (kt <= T_NKT - 3)      asm volatile("s_waitcnt vmcnt(4)" ::: "memory");
        else if (kt == T_NKT - 2) asm volatile("s_waitcnt vmcnt(0)" ::: "memory");
        if (kt < T_NKT - 1) {
            __builtin_amdgcn_sched_barrier(0);
            __builtin_amdgcn_s_barrier();
            __builtin_amdgcn_sched_barrier(0);
        }
    }

    // ---- epilogue: v = in_s * facc + bias; output fake-quant ----
    const float in_s  = in_scale_p[0];
    const float out_s = out_scale_p[0];
    const float out_inv = 1.0f / out_s;
    const float ozp = (float)out_zp_p[0];
    const int col = lane & 15;
    const int rgrp = lane >> 4;
#pragma unroll
    for (int ni = 0; ni < 4; ++ni) {
        const int n = n0 + wc * 64 + ni * 16 + col;
        const float bv = bias_f[n];
#pragma unroll
        for (int mi = 0; mi < 4; ++mi) {
#pragma unroll
            for (int j = 0; j < 4; ++j) {
                const int m = m0 + wr * 64 + mi * 16 + rgrp * 4 + j;
                float v = in_s * facc[mi][ni][j] + bv;
                float q = rintf(v * out_inv) + ozp;
                q = fminf(fmaxf(q, -128.0f), 127.0f);
                out[(size_t)m * N_DIM + n] = (q - ozp) * out_s;
            }
        }
    }
}

// ---------------- fallback path (round-1 proven): bf16 fused ----------------
__global__ void prep_kernel(const int* __restrict__ w_q,
                            const float* __restrict__ w_scale,
                            const int* __restrict__ w_zp,
                            const int* __restrict__ bias_q,
                            const float* __restrict__ bias_scale,
                            __hip_bfloat16* __restrict__ Wb,
                            float* __restrict__ bias_f) {
    const int n = blockIdx.x;
    const int t = threadIdx.x;
    const int k0 = t * 4;
    const int g = k0 >> 7;
    const float s  = w_scale[n * NGRP + g];
    const float zp = (float)w_zp[n * NGRP + g];
    const int4 wq = *reinterpret_cast<const int4*>(w_q + (size_t)n * K_DIM + k0);
    union { ushort4 u; __hip_bfloat16 h[4]; } pk;
    pk.h[0] = __float2bfloat16(((float)wq.x - zp) * s);
    pk.h[1] = __float2bfloat16(((float)wq.y - zp) * s);
    pk.h[2] = __float2bfloat16(((float)wq.z - zp) * s);
    pk.h[3] = __float2bfloat16(((float)wq.w - zp) * s);
    *reinterpret_cast<ushort4*>(Wb + (size_t)n * K_DIM + k0) = pk.u;
    if (t == 0) bias_f[n] = ((float)bias_q[n] - 128.0f) * bias_scale[n];
}

__global__ __launch_bounds__(256) void gemm_fused_kernel(
    const float* __restrict__ x,
    const __hip_bfloat16* __restrict__ Wb,
    const float* __restrict__ bias_f,
    const float* __restrict__ in_scale_p, const int* __restrict__ in_zp_p,
    const float* __restrict__ out_scale_p, const int* __restrict__ out_zp_p,
    float* __restrict__ out)
{
    __shared__ __align__(16) __hip_bfloat16 As[2][FB_BM][FB_BK];
    __shared__ __align__(16) __hip_bfloat16 Bs[2][FB_BN][FB_BK];

    const int t = threadIdx.x;
    const int bid = blockIdx.x;
    const int nt = bid & 7;
    const int mt = bid >> 3;
    const int m0 = mt * FB_BM;
    const int n0 = nt * FB_BN;

    const int wid = t >> 6;
    const int lane = t & 63;
    const int wr = wid >> 1, wc = wid & 1;
    const int lrow = lane & 15;
    const int kslot = lane >> 4;

    const float in_s = in_scale_p[0];
    const float in_inv = 1.0f / in_s;
    const float izp = (float)in_zp_p[0];

    auto stageB = [&](int b, int kt) {
        const int k0 = kt * FB_BK;
#pragma unroll
        for (int j = 0; j < 2; ++j) {
            const int c = (wid * 2 + j) * 64 + lane;
            const int row = c >> 2;
            const int slot = c & 3;
            const __hip_bfloat16* src = Wb + (size_t)(n0 + row) * K_DIM + k0 + slot * 8;
            __builtin_amdgcn_global_load_lds(
                (const __attribute__((address_space(1))) void*)src,
                (__attribute__((address_space(3))) void*)((char*)&Bs[b][0][0] + (wid * 2 + j) * 1024),
                16, 0, 0);
        }
    };
    auto stageA = [&](int b, int kt) {
        const int k0 = kt * FB_BK;
#pragma unroll
        for (int i = 0; i < 4; ++i) {
            const int c = t + 256 * i;
            const int row = c >> 3;
            const int slot = c & 7;
            const float4 v = *reinterpret_cast<const float4*>(
                x + (size_t)(m0 + row) * K_DIM + k0 + slot * 4);
            float vv[4] = {v.x, v.y, v.z, v.w};
            union { ushort4 u; __hip_bfloat16 h[4]; } pk;
#pragma unroll
            for (int e = 0; e < 4; ++e) {
                float q = rintf(vv[e] * in_inv) + izp;
                q = fminf(fmaxf(q, -128.0f), 127.0f);
                pk.h[e] = __float2bfloat16((q - izp) * in_s);
            }
            *reinterpret_cast<ushort4*>(&As[b][row][slot * 4]) = pk.u;
        }
    };

    f32x4 acc[4][4];
#pragma unroll
    for (int mi = 0; mi < 4; ++mi)
#pragma unroll
        for (int ni = 0; ni < 4; ++ni)
            acc[mi][ni] = (f32x4){0.f, 0.f, 0.f, 0.f};

    stageB(0, 0);
    stageA(0, 0);
    __syncthreads();

    for (int kt = 0; kt < FB_NKT; ++kt) {
        const int buf = kt & 1;
        if (kt + 1 < FB_NKT) {
            stageB(buf ^ 1, kt + 1);
            stageA(buf ^ 1, kt + 1);
        }
        bf16x8 af[4], bfr[4];
#pragma unroll
        for (int mi = 0; mi < 4; ++mi)
            af[mi] = *reinterpret_cast<const bf16x8*>(&As[buf][wr * 64 + mi * 16 + lrow][kslot * 8]);
#pragma unroll
        for (int ni = 0; ni < 4; ++ni)
            bfr[ni] = *reinterpret_cast<const bf16x8*>(&Bs[buf][wc * 64 + ni * 16 + lrow][kslot * 8]);
#pragma unroll
        for (int mi = 0; mi < 4; ++mi)
#pragma unroll
            for (int ni = 0; ni < 4; ++ni)
                acc[mi][ni] = __builtin_amdgcn_mfma_f32_16x16x32_bf16(af[mi], bfr[ni], acc[mi][ni], 0, 0, 0);
        __syncthreads();
    }

    const float out_s = out_scale_p[0];
    const float out_inv = 1.0f / out_s;
    const float ozp = (float)out_zp_p[0];
    const int col = lane & 15;
    const int rgrp = lane >> 4;
#pragma unroll
    for (int ni = 0; ni < 4; ++ni) {
        const int n = n0 + wc * 64 + ni * 16 + col;
        const float bv = bias_f[n];
#pragma unroll
        for (int mi = 0; mi < 4; ++mi) {
#pragma unroll
            for (int j = 0; j < 4; ++j) {
                const int m = m0 + wr * 64 + mi * 16 + rgrp * 4 + j;
                float v = acc[mi][ni][j] + bv;
                float q = rintf(v * out_inv) + ozp;
                q = fminf(fmaxf(q, -128.0f), 127.0f);
                out[(size_t)m * N_DIM + n] = (q - ozp) * out_s;
            }
        }
    }
}

extern "C" void kernel_launch(void* const* d_in, const int* in_sizes, int n_in,
                              void* d_out, int out_size, void* d_ws, size_t ws_size,
                              hipStream_t stream) {
    const float* x          = (const float*)d_in[0];
    const int*   w_q        = (const int*)d_in[1];
    const float* w_scale    = (const float*)d_in[2];
    const int*   w_zp       = (const int*)d_in[3];
    const int*   bias_q     = (const int*)d_in[4];
    const float* bias_scale = (const float*)d_in[5];
    const float* in_scale   = (const float*)d_in[6];
    const int*   in_zp      = (const int*)d_in[7];
    const float* out_scale  = (const float*)d_in[8];
    const int*   out_zp     = (const int*)d_in[9];

    const size_t xq8_bytes = (size_t)M_DIM * K_DIM;          // 67.1 MB
    const size_t wd_bytes  = (size_t)N_DIM * K_DIM;          // 1 MB
    const size_t need = xq8_bytes + wd_bytes + N_DIM * sizeof(float);

    if (ws_size >= need) {
        int8_t* Xq8 = (int8_t*)d_ws;
        int8_t* Wd  = (int8_t*)((char*)d_ws + xq8_bytes);
        float* bias_f = (float*)((char*)d_ws + xq8_bytes + wd_bytes);

        prep_wd_kernel<<<N_DIM, 256, 0, stream>>>(w_q, w_zp, bias_q, bias_scale, Wd, bias_f);
        prep_x8_kernel<<<(int)(((size_t)M_DIM * K_DIM) / (256 * 16)), 256, 0, stream>>>(
            x, in_scale, in_zp, Xq8);

        const int grid = (M_DIM / T_BM) * (N_DIM / T_BN);   // 512 * 8 = 4096
        gemm128_i8_kernel<<<grid, 256, 0, stream>>>(Xq8, Wd, w_scale, bias_f,
                                                    in_scale, out_scale, out_zp,
                                                    (float*)d_out);
    } else {
        __hip_bfloat16* Wb = (__hip_bfloat16*)d_ws;
        float* bias_f = (float*)((char*)d_ws + (size_t)N_DIM * K_DIM * sizeof(__hip_bfloat16));

        prep_kernel<<<N_DIM, 256, 0, stream>>>(w_q, w_scale, w_zp, bias_q, bias_scale, Wb, bias_f);
        const int grid = (M_DIM / FB_BM) * (N_DIM / FB_BN);
        gemm_fused_kernel<<<grid, 256, 0, stream>>>(x, Wb, bias_f, in_scale, in_zp,
                                                    out_scale, out_zp, (float*)d_out);
    }
}

// Round 11
// 266.206 us; speedup vs baseline: 1.0446x; 1.0446x over previous
//
#include <hip/hip_runtime.h>
#include <hip/hip_bf16.h>
#include <stdint.h>

// Problem constants (B=8, S=8192, K=1024, N=1024, G=128)
#define M_DIM 65536
#define K_DIM 1024
#define N_DIM 1024
#define NGRP  8

// 128x128 i8 GEMM, BK=64, static dbuf, group-pair i32 accumulation
#define T_BM 128
#define T_BN 128
#define T_BK 64
#define T_NKT (K_DIM / T_BK)    // 16 tiles = 8 groups x 2

// fallback geometry (round-1 fused kernel)
#define FB_BM 128
#define FB_BN 128
#define FB_BK 32
#define FB_NKT (K_DIM / FB_BK)

typedef float f32x4 __attribute__((ext_vector_type(4)));
typedef int   ix4   __attribute__((ext_vector_type(4)));
typedef __bf16 bf16x8 __attribute__((ext_vector_type(8)));

// ---------------- prep: wd = w_q - w_zp (int8) [N][K], bias -> f32 ----------------
__global__ void prep_wd_kernel(const int* __restrict__ w_q,
                               const int* __restrict__ w_zp,
                               const int* __restrict__ bias_q,
                               const float* __restrict__ bias_scale,
                               int8_t* __restrict__ Wd,
                               float* __restrict__ bias_f) {
    const int n = blockIdx.x;       // 0..1023
    const int t = threadIdx.x;      // 0..255
    const int k0 = t * 4;
    const int g = k0 >> 7;
    const int zp = w_zp[n * NGRP + g];
    const int4 wq = *reinterpret_cast<const int4*>(w_q + (size_t)n * K_DIM + k0);
    union { int u; int8_t b[4]; } pk;
    pk.b[0] = (int8_t)(wq.x - zp);
    pk.b[1] = (int8_t)(wq.y - zp);
    pk.b[2] = (int8_t)(wq.z - zp);
    pk.b[3] = (int8_t)(wq.w - zp);
    *reinterpret_cast<int*>(Wd + (size_t)n * K_DIM + k0) = pk.u;
    if (t == 0) bias_f[n] = ((float)bias_q[n] - 128.0f) * bias_scale[n];
}

// ---------------- prep: fake-quant x -> int8 codes [M][K] ----------------
__global__ __launch_bounds__(256) void prep_x8_kernel(
    const float* __restrict__ x,
    const float* __restrict__ in_scale_p, const int* __restrict__ in_zp_p,
    int8_t* __restrict__ Xq)
{
    const float s = in_scale_p[0];
    const float inv = 1.0f / s;
    const float zp = (float)in_zp_p[0];
    const size_t i = ((size_t)blockIdx.x * 256 + threadIdx.x) * 16;
    float vv[16];
#pragma unroll
    for (int c = 0; c < 4; ++c) {
        const float4 v = *reinterpret_cast<const float4*>(x + i + c * 4);
        vv[c * 4 + 0] = v.x; vv[c * 4 + 1] = v.y;
        vv[c * 4 + 2] = v.z; vv[c * 4 + 3] = v.w;
    }
    union { int4 u; int8_t b[16]; } pk;
#pragma unroll
    for (int e = 0; e < 16; ++e) {
        float q = rintf(vv[e] * inv) + zp;       // RNE matches jnp.round
        q = fminf(fmaxf(q, -128.0f), 127.0f);
        pk.b[e] = (int8_t)(q - zp);
    }
    *reinterpret_cast<int4*>(Xq + i) = pk.u;
}

// ---------------- 128x128 i8 GEMM: r9 skeleton + group-pair accumulation ----------------
// 256 thr = 4 waves (2x2), wave owns 64x64. Static dbuf (buf0/buf1), plain
// __syncthreads (drains vmcnt+lgkm; proven r9 at 154us).
// Group g = tiles {2g (buf0), 2g+1 (buf1)}:
//   even phase: stage buf1<-tile 2g+1 | read buf0 | 16 MFMA C=0 -> it0 | sync
//   odd  phase: stage buf0<-tile 2g+2 | read buf1 | 16 MFMA C=it0 (HW acc)
//               | ONE CVT: facc += ws*(float)it0 (128 VALU, was 256) | sync
// Exactness: S_g = int32 dot over K=128, |S|<=2.5e5 < 2^24 -> (float) exact.
// in_s folded into WS at fill (epilogue: facc + bias only).
__global__ __launch_bounds__(256) void gemm128_i8g_kernel(
    const int8_t* __restrict__ Xq,
    const int8_t* __restrict__ Wd,
    const float* __restrict__ w_scale,
    const float* __restrict__ bias_f,
    const float* __restrict__ in_scale_p,
    const float* __restrict__ out_scale_p, const int* __restrict__ out_zp_p,
    float* __restrict__ out)
{
    __shared__ __align__(16) int8_t Abuf[2][T_BM * T_BK];   // 2 x 8 KB
    __shared__ __align__(16) int8_t Bbuf[2][T_BN * T_BK];   // 2 x 8 KB
    __shared__ float WS[NGRP * T_BN];                        // 4 KB [g][n_local]

    const int t = threadIdx.x;
    // bijective XCD swizzle: grid=4096, 8 XCDs, 512 blocks/XCD;
    // consecutive local bids share the A panel (mt) across nt=0..7.
    const int bid = (blockIdx.x & 7) * 512 + (blockIdx.x >> 3);
    const int nt = bid & 7;
    const int mt = bid >> 3;
    const int m0 = mt * T_BM;
    const int n0 = nt * T_BN;

    const int wid = t >> 6;
    const int lane = t & 63;
    const int wr = wid >> 1, wc = wid & 1;     // 2x2 waves, each owns 64x64
    const int lrow = lane & 15;
    const int kslot = lane >> 4;               // 16B k-chunk within 64B row
    const int koff = ((kslot ^ ((lrow >> 1) & 3)) << 4);   // 0-conflict (r2-r9)
    const int widoff = wid * 1024;

    const int8_t* Abase = Xq + (size_t)m0 * K_DIM;
    const int8_t* Bbase = Wd + (size_t)n0 * K_DIM;

    // ---- preload w_scale panel [g][n_local], folded with in_s ----
    {
        const float in_s = in_scale_p[0];
        const int nl = t >> 1;                 // 0..127
        const int g4 = (t & 1) * 4;
        const float4 wv = *reinterpret_cast<const float4*>(
            w_scale + (size_t)(n0 + nl) * NGRP + g4);
        WS[(g4 + 0) * T_BN + nl] = wv.x * in_s;
        WS[(g4 + 1) * T_BN + nl] = wv.y * in_s;
        WS[(g4 + 2) * T_BN + nl] = wv.z * in_s;
        WS[(g4 + 3) * T_BN + nl] = wv.w * in_s;
    }

    // stage one 128x64B tile (512 chunks, 2/thread), pre-swizzled source
    auto stage = [&](int8_t* dst, const int8_t* panel, int kt) {
        const int k0 = kt * T_BK;
#pragma unroll
        for (int j = 0; j < 2; ++j) {
            const int c = j * 256 + t;                 // 16B chunk id 0..511
            const int r = c >> 2;                      // row 0..127
            const int sl = (c & 3) ^ ((r >> 1) & 3);   // logical k-slot at phys slot
            const int8_t* src = panel + (size_t)r * K_DIM + k0 + sl * 16;
            __builtin_amdgcn_global_load_lds(
                (const __attribute__((address_space(1))) void*)src,
                (__attribute__((address_space(3))) void*)(dst + j * 4096 + widoff),
                16, 0, 0);
        }
    };

    f32x4 facc[4][4];
#pragma unroll
    for (int mi = 0; mi < 4; ++mi)
#pragma unroll
        for (int ni = 0; ni < 4; ++ni)
            facc[mi][ni] = (f32x4){0.f, 0.f, 0.f, 0.f};

    // prologue: stage tile 0 into buf0 (WS + DMA drained by syncthreads)
    stage(&Abuf[0][0], Abase, 0);
    stage(&Bbuf[0][0], Bbase, 0);
    __syncthreads();

    ix4 it0[4][4];

#pragma unroll 1
    for (int g = 0; g < NGRP; ++g) {
        // ---- even phase: tile 2g in buf0 ----
        stage(&Abuf[1][0], Abase, 2 * g + 1);
        stage(&Bbuf[1][0], Bbase, 2 * g + 1);
        {
            ix4 af[4], bfr[4];
#pragma unroll
            for (int i = 0; i < 4; ++i) {
                const int arow = wr * 64 + i * 16 + lrow;
                af[i] = *reinterpret_cast<const ix4*>(&Abuf[0][arow * 64 + koff]);
            }
#pragma unroll
            for (int i = 0; i < 4; ++i) {
                const int brow = wc * 64 + i * 16 + lrow;
                bfr[i] = *reinterpret_cast<const ix4*>(&Bbuf[0][brow * 64 + koff]);
            }
#pragma unroll
            for (int mi = 0; mi < 4; ++mi)
#pragma unroll
                for (int ni = 0; ni < 4; ++ni)
                    it0[mi][ni] = __builtin_amdgcn_mfma_i32_16x16x64_i8(
                        af[mi], bfr[ni], (ix4){0, 0, 0, 0}, 0, 0, 0);
        }
        __syncthreads();

        // ---- odd phase: tile 2g+1 in buf1, HW-accumulate into it0 ----
        if (g + 1 < NGRP) {
            stage(&Abuf[0][0], Abase, 2 * g + 2);
            stage(&Bbuf[0][0], Bbase, 2 * g + 2);
        }
        {
            ix4 af[4], bfr[4];
#pragma unroll
            for (int i = 0; i < 4; ++i) {
                const int arow = wr * 64 + i * 16 + lrow;
                af[i] = *reinterpret_cast<const ix4*>(&Abuf[1][arow * 64 + koff]);
            }
#pragma unroll
            for (int i = 0; i < 4; ++i) {
                const int brow = wc * 64 + i * 16 + lrow;
                bfr[i] = *reinterpret_cast<const ix4*>(&Bbuf[1][brow * 64 + koff]);
            }
            float wsv[4];
#pragma unroll
            for (int ni = 0; ni < 4; ++ni)
                wsv[ni] = WS[g * T_BN + wc * 64 + ni * 16 + lrow];
#pragma unroll
            for (int mi = 0; mi < 4; ++mi)
#pragma unroll
                for (int ni = 0; ni < 4; ++ni)
                    it0[mi][ni] = __builtin_amdgcn_mfma_i32_16x16x64_i8(
                        af[mi], bfr[ni], it0[mi][ni], 0, 0, 0);
            // one CVT per group (exact: |S| < 2^24)
#pragma unroll
            for (int mi = 0; mi < 4; ++mi)
#pragma unroll
                for (int ni = 0; ni < 4; ++ni)
#pragma unroll
                    for (int e = 0; e < 4; ++e)
                        facc[mi][ni][e] += wsv[ni] * (float)it0[mi][ni][e];
        }
        __syncthreads();
    }

    // ---- epilogue: v = facc + bias (in_s already folded); output fake-quant ----
    const float out_s = out_scale_p[0];
    const float out_inv = 1.0f / out_s;
    const float ozp = (float)out_zp_p[0];
    const int col = lane & 15;
    const int rgrp = lane >> 4;
#pragma unroll
    for (int ni = 0; ni < 4; ++ni) {
        const int n = n0 + wc * 64 + ni * 16 + col;
        const float bv = bias_f[n];
#pragma unroll
        for (int mi = 0; mi < 4; ++mi) {
#pragma unroll
            for (int j = 0; j < 4; ++j) {
                const int m = m0 + wr * 64 + mi * 16 + rgrp * 4 + j;
                float v = facc[mi][ni][j] + bv;
                float q = rintf(v * out_inv) + ozp;
                q = fminf(fmaxf(q, -128.0f), 127.0f);
                out[(size_t)m * N_DIM + n] = (q - ozp) * out_s;
            }
        }
    }
}

// ---------------- fallback path (round-1 proven): bf16 fused ----------------
__global__ void prep_kernel(const int* __restrict__ w_q,
                            const float* __restrict__ w_scale,
                            const int* __restrict__ w_zp,
                            const int* __restrict__ bias_q,
                            const float* __restrict__ bias_scale,
                            __hip_bfloat16* __restrict__ Wb,
                            float* __restrict__ bias_f) {
    const int n = blockIdx.x;
    const int t = threadIdx.x;
    const int k0 = t * 4;
    const int g = k0 >> 7;
    const float s  = w_scale[n * NGRP + g];
    const float zp = (float)w_zp[n * NGRP + g];
    const int4 wq = *reinterpret_cast<const int4*>(w_q + (size_t)n * K_DIM + k0);
    union { ushort4 u; __hip_bfloat16 h[4]; } pk;
    pk.h[0] = __float2bfloat16(((float)wq.x - zp) * s);
    pk.h[1] = __float2bfloat16(((float)wq.y - zp) * s);
    pk.h[2] = __float2bfloat16(((float)wq.z - zp) * s);
    pk.h[3] = __float2bfloat16(((float)wq.w - zp) * s);
    *reinterpret_cast<ushort4*>(Wb + (size_t)n * K_DIM + k0) = pk.u;
    if (t == 0) bias_f[n] = ((float)bias_q[n] - 128.0f) * bias_scale[n];
}

__global__ __launch_bounds__(256) void gemm_fused_kernel(
    const float* __restrict__ x,
    const __hip_bfloat16* __restrict__ Wb,
    const float* __restrict__ bias_f,
    const float* __restrict__ in_scale_p, const int* __restrict__ in_zp_p,
    const float* __restrict__ out_scale_p, const int* __restrict__ out_zp_p,
    float* __restrict__ out)
{
    __shared__ __align__(16) __hip_bfloat16 As[2][FB_BM][FB_BK];
    __shared__ __align__(16) __hip_bfloat16 Bs[2][FB_BN][FB_BK];

    const int t = threadIdx.x;
    const int bid = blockIdx.x;
    const int nt = bid & 7;
    const int mt = bid >> 3;
    const int m0 = mt * FB_BM;
    const int n0 = nt * FB_BN;

    const int wid = t >> 6;
    const int lane = t & 63;
    const int wr = wid >> 1, wc = wid & 1;
    const int lrow = lane & 15;
    const int kslot = lane >> 4;

    const float in_s = in_scale_p[0];
    const float in_inv = 1.0f / in_s;
    const float izp = (float)in_zp_p[0];

    auto stageB = [&](int b, int kt) {
        const int k0 = kt * FB_BK;
#pragma unroll
        for (int j = 0; j < 2; ++j) {
            const int c = (wid * 2 + j) * 64 + lane;
            const int row = c >> 2;
            const int slot = c & 3;
            const __hip_bfloat16* src = Wb + (size_t)(n0 + row) * K_DIM + k0 + slot * 8;
            __builtin_amdgcn_global_load_lds(
                (const __attribute__((address_space(1))) void*)src,
                (__attribute__((address_space(3))) void*)((char*)&Bs[b][0][0] + (wid * 2 + j) * 1024),
                16, 0, 0);
        }
    };
    auto stageA = [&](int b, int kt) {
        const int k0 = kt * FB_BK;
#pragma unroll
        for (int i = 0; i < 4; ++i) {
            const int c = t + 256 * i;
            const int row = c >> 3;
            const int slot = c & 7;
            const float4 v = *reinterpret_cast<const float4*>(
                x + (size_t)(m0 + row) * K_DIM + k0 + slot * 4);
            float vv[4] = {v.x, v.y, v.z, v.w};
            union { ushort4 u; __hip_bfloat16 h[4]; } pk;
#pragma unroll
            for (int e = 0; e < 4; ++e) {
                float q = rintf(vv[e] * in_inv) + izp;
                q = fminf(fmaxf(q, -128.0f), 127.0f);
                pk.h[e] = __float2bfloat16((q - izp) * in_s);
            }
            *reinterpret_cast<ushort4*>(&As[b][row][slot * 4]) = pk.u;
        }
    };

    f32x4 acc[4][4];
#pragma unroll
    for (int mi = 0; mi < 4; ++mi)
#pragma unroll
        for (int ni = 0; ni < 4; ++ni)
            acc[mi][ni] = (f32x4){0.f, 0.f, 0.f, 0.f};

    stageB(0, 0);
    stageA(0, 0);
    __syncthreads();

    for (int kt = 0; kt < FB_NKT; ++kt) {
        const int buf = kt & 1;
        if (kt + 1 < FB_NKT) {
            stageB(buf ^ 1, kt + 1);
            stageA(buf ^ 1, kt + 1);
        }
        bf16x8 af[4], bfr[4];
#pragma unroll
        for (int mi = 0; mi < 4; ++mi)
            af[mi] = *reinterpret_cast<const bf16x8*>(&As[buf][wr * 64 + mi * 16 + lrow][kslot * 8]);
#pragma unroll
        for (int ni = 0; ni < 4; ++ni)
            bfr[ni] = *reinterpret_cast<const bf16x8*>(&Bs[buf][wc * 64 + ni * 16 + lrow][kslot * 8]);
#pragma unroll
        for (int mi = 0; mi < 4; ++mi)
#pragma unroll
            for (int ni = 0; ni < 4; ++ni)
                acc[mi][ni] = __builtin_amdgcn_mfma_f32_16x16x32_bf16(af[mi], bfr[ni], acc[mi][ni], 0, 0, 0);
        __syncthreads();
    }

    const float out_s = out_scale_p[0];
    const float out_inv = 1.0f / out_s;
    const float ozp = (float)out_zp_p[0];
    const int col = lane & 15;
    const int rgrp = lane >> 4;
#pragma unroll
    for (int ni = 0; ni < 4; ++ni) {
        const int n = n0 + wc * 64 + ni * 16 + col;
        const float bv = bias_f[n];
#pragma unroll
        for (int mi = 0; mi < 4; ++mi) {
#pragma unroll
            for (int j = 0; j < 4; ++j) {
                const int m = m0 + wr * 64 + mi * 16 + rgrp * 4 + j;
                float v = acc[mi][ni][j] + bv;
                float q = rintf(v * out_inv) + ozp;
                q = fminf(fmaxf(q, -128.0f), 127.0f);
                out[(size_t)m * N_DIM + n] = (q - ozp) * out_s;
            }
        }
    }
}

extern "C" void kernel_launch(void* const* d_in, const int* in_sizes, int n_in,
                              void* d_out, int out_size, void* d_ws, size_t ws_size,
                              hipStream_t stream) {
    const float* x          = (const float*)d_in[0];
    const int*   w_q        = (const int*)d_in[1];
    const float* w_scale    = (const float*)d_in[2];
    const int*   w_zp       = (const int*)d_in[3];
    const int*   bias_q     = (const int*)d_in[4];
    const float* bias_scale = (const float*)d_in[5];
    const float* in_scale   = (const float*)d_in[6];
    const int*   in_zp      = (const int*)d_in[7];
    const float* out_scale  = (const float*)d_in[8];
    const int*   out_zp     = (const int*)d_in[9];

    const size_t xq8_bytes = (size_t)M_DIM * K_DIM;          // 67.1 MB
    const size_t wd_bytes  = (size_t)N_DIM * K_DIM;          // 1 MB
    const size_t need = xq8_bytes + wd_bytes + N_DIM * sizeof(float);

    if (ws_size >= need) {
        int8_t* Xq8 = (int8_t*)d_ws;
        int8_t* Wd  = (int8_t*)((char*)d_ws + xq8_bytes);
        float* bias_f = (float*)((char*)d_ws + xq8_bytes + wd_bytes);

        prep_wd_kernel<<<N_DIM, 256, 0, stream>>>(w_q, w_zp, bias_q, bias_scale, Wd, bias_f);
        prep_x8_kernel<<<(int)(((size_t)M_DIM * K_DIM) / (256 * 16)), 256, 0, stream>>>(
            x, in_scale, in_zp, Xq8);

        const int grid = (M_DIM / T_BM) * (N_DIM / T_BN);   // 512 * 8 = 4096
        gemm128_i8g_kernel<<<grid, 256, 0, stream>>>(Xq8, Wd, w_scale, bias_f,
                                                     in_scale, out_scale, out_zp,
                                                     (float*)d_out);
    } else {
        __hip_bfloat16* Wb = (__hip_bfloat16*)d_ws;
        float* bias_f = (float*)((char*)d_ws + (size_t)N_DIM * K_DIM * sizeof(__hip_bfloat16));

        prep_kernel<<<N_DIM, 256, 0, stream>>>(w_q, w_scale, w_zp, bias_q, bias_scale, Wb, bias_f);
        const int grid = (M_DIM / FB_BM) * (N_DIM / FB_BN);
        gemm_fused_kernel<<<grid, 256, 0, stream>>>(x, Wb, bias_f, in_scale, in_zp,
                                                    out_scale, out_zp, (float*)d_out);
    }
}